// Round 3
// baseline (801.992 us; speedup 1.0000x reference)
//
#include <hip/hip_runtime.h>

// out[d] = sum_{e: dst[e]==d} x[src[e]]   (N=100k, E=1.6M, D=32 f32)
//
// Round-2 lesson: fine-grained counting sort writes 4B to temporally-scattered
// positions -> 1.6M dirty 64B lines -> 102 MB write traffic. Fix: bucket-level
// sort (128 nodes/bucket) so concurrent writers land on consecutive addresses,
// then finish the segment reduction in a 16KB LDS accumulator per bucket.

#define D_FEAT 32
#define BKT_SHIFT 7
#define BKT_NODES 128          // nodes per bucket
#define MAX_NB 1024            // max buckets supported by scan/hist LDS
typedef unsigned int u32;

// ---------------- bucket pipeline ----------------

__global__ void __launch_bounds__(256)
k_zero_u32(u32* __restrict__ p, int n) {
    int i = blockIdx.x * blockDim.x + threadIdx.x;
    if (i < n) p[i] = 0u;
}

// Per-block LDS histogram of bucket ids, flushed with global atomics.
__global__ void __launch_bounds__(256)
k_bhist(const int* __restrict__ dst, u32* __restrict__ cnt,
        int n_edges, int nb, int per_block) {
    __shared__ u32 h[MAX_NB];
    for (int i = threadIdx.x; i < nb; i += 256) h[i] = 0u;
    __syncthreads();
    int beg = blockIdx.x * per_block;
    int end = min(beg + per_block, n_edges);
    for (int e = beg + threadIdx.x; e < end; e += 256)
        atomicAdd(&h[dst[e] >> BKT_SHIFT], 1u);
    __syncthreads();
    for (int i = threadIdx.x; i < nb; i += 256) {
        u32 v = h[i];
        if (v) atomicAdd(&cnt[i], v);
    }
}

// Single-block exclusive scan of nb (<=1024) bucket counts.
// cnt may alias cur (read-before-write per thread).
__global__ void __launch_bounds__(1024)
k_bscan(const u32* cnt, u32* offs, u32* cur, int nb, u32 total) {
    __shared__ u32 s[1024];
    int t = threadIdx.x;
    u32 v = (t < nb) ? cnt[t] : 0u;
    s[t] = v;
    __syncthreads();
    for (int off = 1; off < 1024; off <<= 1) {
        u32 y = (t >= off) ? s[t - off] : 0u;
        __syncthreads();
        if (t >= off) s[t] += y;
        __syncthreads();
    }
    u32 exc = s[t] - v;
    if (t < nb) { offs[t] = exc; cur[t] = exc; }
    if (t == 0) offs[nb] = total;
}

// Scatter packed (src | dlocal<<17) into bucket regions. Per-bucket cursor
// means concurrent writers get consecutive positions -> coalesced lines.
__global__ void __launch_bounds__(256)
k_bscatter(const int* __restrict__ src, const int* __restrict__ dst,
           u32* __restrict__ cur, u32* __restrict__ bin, int n_edges) {
    int e = blockIdx.x * blockDim.x + threadIdx.x;
    if (e >= n_edges) return;
    int d = dst[e];
    int b = d >> BKT_SHIFT;
    u32 pos = atomicAdd(&cur[b], 1u);
    bin[pos] = (u32)src[e] | ((u32)(d & (BKT_NODES - 1)) << 17);
}

// One block per bucket: LDS accumulator acc[c*128+dlocal] (bank = dlocal%32,
// random dlocal per lane -> ~2-way conflicts, free). ds_add_f32 atomics.
__global__ void __launch_bounds__(256)
k_bgather(const float* __restrict__ x, const u32* __restrict__ offs,
          const u32* __restrict__ bin, float* __restrict__ out, int n_nodes) {
    __shared__ float acc[D_FEAT * BKT_NODES];   // 16 KB
    int b = blockIdx.x;
    int t = threadIdx.x;
    for (int i = t; i < D_FEAT * BKT_NODES; i += 256) acc[i] = 0.f;
    __syncthreads();
    u32 beg = offs[b], end = offs[b + 1];
    const float4* x4 = (const float4*)x;
    for (u32 k = beg + t; k < end; k += 256) {
        u32 p = bin[k];
        u32 s = p & 0x1FFFFu;
        u32 d = p >> 17;
#pragma unroll
        for (int q = 0; q < 8; ++q) {
            float4 v = x4[(size_t)s * 8 + q];
            unsafeAtomicAdd(&acc[(4 * q + 0) * BKT_NODES + d], v.x);
            unsafeAtomicAdd(&acc[(4 * q + 1) * BKT_NODES + d], v.y);
            unsafeAtomicAdd(&acc[(4 * q + 2) * BKT_NODES + d], v.z);
            unsafeAtomicAdd(&acc[(4 * q + 3) * BKT_NODES + d], v.w);
        }
    }
    __syncthreads();
    int node0 = b * BKT_NODES;
    int nloc = min(BKT_NODES, n_nodes - node0);
    float4* o4 = (float4*)out;
    for (int i = t; i < nloc * 8; i += 256) {
        int d = i >> 3, q = i & 7;
        float4 v;
        v.x = acc[(4 * q + 0) * BKT_NODES + d];
        v.y = acc[(4 * q + 1) * BKT_NODES + d];
        v.z = acc[(4 * q + 2) * BKT_NODES + d];
        v.w = acc[(4 * q + 3) * BKT_NODES + d];
        o4[(size_t)(node0 + d) * 8 + q] = v;
    }
}

// ---------------- fallback (round-1 atomic path) ----------------

__global__ void __launch_bounds__(256)
mp_zero_kernel(float* __restrict__ out, int n) {
    int i = blockIdx.x * blockDim.x + threadIdx.x;
    if (i < n) out[i] = 0.0f;
}

__global__ void __launch_bounds__(256)
mp_scatter_kernel(const float* __restrict__ x, const int* __restrict__ src,
                  const int* __restrict__ dst, float* __restrict__ out,
                  int n_edges) {
    int idx = blockIdx.x * blockDim.x + threadIdx.x;
    if (idx >= n_edges * 8) return;
    int e = idx >> 3;
    int c = idx & 7;
    const float4 v = *reinterpret_cast<const float4*>(x + (size_t)src[e] * D_FEAT + c * 4);
    float* o = out + (size_t)dst[e] * D_FEAT + c * 4;
    unsafeAtomicAdd(o + 0, v.x);
    unsafeAtomicAdd(o + 1, v.y);
    unsafeAtomicAdd(o + 2, v.z);
    unsafeAtomicAdd(o + 3, v.w);
}

// ---------------- launch ----------------

extern "C" void kernel_launch(void* const* d_in, const int* in_sizes, int n_in,
                              void* d_out, int out_size, void* d_ws, size_t ws_size,
                              hipStream_t stream) {
    const float* x = (const float*)d_in[0];
    const int* edge_index = (const int*)d_in[1];
    int n_edges = in_sizes[1] / 2;
    const int* src = edge_index;            // row 0: source j
    const int* dst = edge_index + n_edges;  // row 1: target i
    float* out = (float*)d_out;
    int n_nodes = out_size / D_FEAT;

    int nb = (n_nodes + BKT_NODES - 1) / BKT_NODES;   // 782 for N=100k

    // ws layout (u32): offs[nb+1] | cur[nb] | bin[E]
    size_t need = ((size_t)(nb + 1) + nb + n_edges) * sizeof(u32);
    bool ok = (ws_size >= need) && (nb <= MAX_NB) && (n_nodes <= (1 << 17));
    if (!ok) {
        mp_zero_kernel<<<(out_size + 255) / 256, 256, 0, stream>>>(out, out_size);
        int total = n_edges * 8;
        mp_scatter_kernel<<<(total + 255) / 256, 256, 0, stream>>>(x, src, dst, out, n_edges);
        return;
    }

    u32* offs = (u32*)d_ws;
    u32* cur  = offs + (nb + 1);
    u32* bin  = cur + nb;

    const int per_block = 8192;                        // 196 hist blocks
    int hist_blocks = (n_edges + per_block - 1) / per_block;

    k_zero_u32<<<(nb + 255) / 256, 256, 0, stream>>>(cur, nb);
    k_bhist<<<hist_blocks, 256, 0, stream>>>(dst, cur, n_edges, nb, per_block);
    k_bscan<<<1, 1024, 0, stream>>>(cur, offs, cur, nb, (u32)n_edges);
    k_bscatter<<<(n_edges + 255) / 256, 256, 0, stream>>>(src, dst, cur, bin, n_edges);
    k_bgather<<<nb, 256, 0, stream>>>(x, offs, bin, out, n_nodes);
}

// Round 4
// 162.226 us; speedup vs baseline: 4.9437x; 4.9437x over previous
//
#include <hip/hip_runtime.h>

// out[d] = sum_{e: dst[e]==d} x[src[e]]   (N=100k, E=1.6M, D=32 f32)
//
// Round-3 lesson: global atomic cursors serialize (1.6M RMWs on 782 addrs =
// 376us) and cross-XCD writers shred cache lines (71MB writes). Fix: radix-
// partition with BLOCK-LOCAL ranking — per-block histogram + global scan
// assigns each (block,bucket) a private contiguous run; placement uses LDS
// atomics only and writes are block-private coalesced runs. Gather sorts each
// 2048-entry pass by local node in LDS, then register-accumulates (no LDS
// f32 atomics), with 8 lanes fetching one 128B x-row coalesced.

#define D_FEAT 32
#define BKT_SHIFT 7
#define BKT_NODES 128
#define MAX_NB 1024
#define CHUNK 8192            // edges per block (hist/scatter)
#define GCHUNK 2048           // entries per LDS pass (gather)
typedef unsigned int u32;

__global__ void __launch_bounds__(256)
k_zero_u32(u32* __restrict__ p, int n) {
    int i = blockIdx.x * blockDim.x + threadIdx.x;
    if (i < n) p[i] = 0u;
}

// Per-block bucket histogram -> hist[block][bucket]; bucket totals via atomics.
__global__ void __launch_bounds__(256)
k_hist(const int* __restrict__ dst, u32* __restrict__ hist,
       u32* __restrict__ total, int n_edges, int nb) {
    __shared__ u32 h[MAX_NB];
    for (int i = threadIdx.x; i < nb; i += 256) h[i] = 0u;
    __syncthreads();
    int beg = blockIdx.x * CHUNK;
    int end = min(beg + CHUNK, n_edges);
    for (int e = beg + threadIdx.x; e < end; e += 256)
        atomicAdd(&h[((u32)dst[e]) >> BKT_SHIFT], 1u);
    __syncthreads();
    u32* row = hist + (size_t)blockIdx.x * nb;
    for (int i = threadIdx.x; i < nb; i += 256) {
        u32 v = h[i];
        row[i] = v;                       // coalesced
        if (v) atomicAdd(&total[i], v);   // 153k atomics total, uncontended-ish
    }
}

// Exclusive scan of bucket totals (nb <= 1024), one block.
__global__ void __launch_bounds__(1024)
k_scan(const u32* __restrict__ total, u32* __restrict__ offs, int nb, u32 tot) {
    __shared__ u32 s[1024];
    int t = threadIdx.x;
    u32 v = (t < nb) ? total[t] : 0u;
    s[t] = v;
    __syncthreads();
    for (int off = 1; off < 1024; off <<= 1) {
        u32 y = (t >= off) ? s[t - off] : 0u;
        __syncthreads();
        if (t >= off) s[t] += y;
        __syncthreads();
    }
    if (t < nb) offs[t] = s[t] - v;
    if (t == 0) offs[nb] = tot;
}

// Per-bucket prefix over blocks: hist[j][b] <- offs[b] + sum_{j'<j} hist[j'][b].
// One block per bucket; nblk <= 256.
__global__ void __launch_bounds__(256)
k_rank(u32* __restrict__ hist, const u32* __restrict__ offs, int nb, int nblk) {
    __shared__ u32 s[256];
    int b = blockIdx.x, t = threadIdx.x;
    u32 v = (t < nblk) ? hist[(size_t)t * nb + b] : 0u;
    s[t] = v;
    __syncthreads();
    for (int off = 1; off < 256; off <<= 1) {
        u32 y = (t >= off) ? s[t - off] : 0u;
        __syncthreads();
        if (t >= off) s[t] += y;
        __syncthreads();
    }
    if (t < nblk) hist[(size_t)t * nb + b] = offs[b] + s[t] - v;
}

// Placement: LDS cursors preloaded with this block's private run bases.
// All writes land in block-private contiguous runs -> coalesced, no global RMW.
__global__ void __launch_bounds__(256)
k_scatter(const int* __restrict__ src, const int* __restrict__ dst,
          const u32* __restrict__ hist, u32* __restrict__ bin,
          int n_edges, int nb) {
    __shared__ u32 cur[MAX_NB];
    const u32* row = hist + (size_t)blockIdx.x * nb;
    for (int i = threadIdx.x; i < nb; i += 256) cur[i] = row[i];
    __syncthreads();
    int beg = blockIdx.x * CHUNK;
    int end = min(beg + CHUNK, n_edges);
    for (int e = beg + threadIdx.x; e < end; e += 256) {
        u32 d = (u32)dst[e];
        u32 pos = atomicAdd(&cur[d >> BKT_SHIFT], 1u);   // LDS-only RMW
        bin[pos] = (u32)src[e] | ((d & (BKT_NODES - 1)) << 17);
    }
}

// One block per bucket. Per 2048-entry pass: LDS sort by dlocal (hist+scan+
// rank), then 1024 (node,q) tasks register-accumulate their segment.
__global__ void __launch_bounds__(256)
k_gather(const float* __restrict__ x, const u32* __restrict__ offs,
         const u32* __restrict__ bin, float* __restrict__ out, int n_nodes) {
    __shared__ u32 s_ent[GCHUNK];
    __shared__ u32 s_srt[GCHUNK];
    __shared__ u32 s_off[BKT_NODES + 1];
    __shared__ u32 s_cur[BKT_NODES];
    __shared__ u32 s_scan[BKT_NODES];
    int b = blockIdx.x, t = threadIdx.x;
    u32 beg = offs[b], end = offs[b + 1];
    const float4* x4 = (const float4*)x;
    float4 acc[4];
#pragma unroll
    for (int k = 0; k < 4; ++k) acc[k] = make_float4(0.f, 0.f, 0.f, 0.f);

    for (u32 c0 = beg; c0 < end; c0 += GCHUNK) {
        int m = (int)min((u32)GCHUNK, end - c0);
        for (int i = t; i < m; i += 256) s_ent[i] = bin[c0 + i];
        if (t < BKT_NODES) s_cur[t] = 0u;
        __syncthreads();
        for (int i = t; i < m; i += 256) atomicAdd(&s_cur[s_ent[i] >> 17], 1u);
        __syncthreads();
        u32 v = 0u;
        if (t < BKT_NODES) { v = s_cur[t]; s_scan[t] = v; }
        __syncthreads();
        for (int off = 1; off < BKT_NODES; off <<= 1) {
            u32 y = 0u;
            if (t < BKT_NODES && t >= off) y = s_scan[t - off];
            __syncthreads();
            if (t < BKT_NODES && t >= off) s_scan[t] += y;
            __syncthreads();
        }
        if (t < BKT_NODES) { u32 ex = s_scan[t] - v; s_off[t] = ex; s_cur[t] = ex; }
        if (t == 0) s_off[BKT_NODES] = (u32)m;
        __syncthreads();
        for (int i = t; i < m; i += 256) {
            u32 p = s_ent[i];
            u32 pos = atomicAdd(&s_cur[p >> 17], 1u);
            s_srt[pos] = p & 0x1FFFFu;
        }
        __syncthreads();
#pragma unroll
        for (int k = 0; k < 4; ++k) {
            int task = t + 256 * k;
            int node = task >> 3, q = task & 7;
            u32 j1 = s_off[node + 1];
            for (u32 j = s_off[node]; j < j1; ++j) {
                u32 s = s_srt[j];                       // LDS broadcast to 8 lanes
                float4 xv = x4[(size_t)s * 8 + q];      // 8 lanes = one 128B row
                acc[k].x += xv.x; acc[k].y += xv.y;
                acc[k].z += xv.z; acc[k].w += xv.w;
            }
        }
        __syncthreads();
    }

    int node0 = b * BKT_NODES;
    int nloc = min(BKT_NODES, n_nodes - node0);
    float4* o4 = (float4*)out;
#pragma unroll
    for (int k = 0; k < 4; ++k) {
        int task = t + 256 * k;
        int node = task >> 3, q = task & 7;
        if (node < nloc) o4[(size_t)(node0 + node) * 8 + q] = acc[k];
    }
}

// ---------------- fallback (round-1 atomic path) ----------------

__global__ void __launch_bounds__(256)
mp_zero_kernel(float* __restrict__ out, int n) {
    int i = blockIdx.x * blockDim.x + threadIdx.x;
    if (i < n) out[i] = 0.0f;
}

__global__ void __launch_bounds__(256)
mp_scatter_kernel(const float* __restrict__ x, const int* __restrict__ src,
                  const int* __restrict__ dst, float* __restrict__ out,
                  int n_edges) {
    int idx = blockIdx.x * blockDim.x + threadIdx.x;
    if (idx >= n_edges * 8) return;
    int e = idx >> 3;
    int c = idx & 7;
    const float4 v = *reinterpret_cast<const float4*>(x + (size_t)src[e] * D_FEAT + c * 4);
    float* o = out + (size_t)dst[e] * D_FEAT + c * 4;
    unsafeAtomicAdd(o + 0, v.x);
    unsafeAtomicAdd(o + 1, v.y);
    unsafeAtomicAdd(o + 2, v.z);
    unsafeAtomicAdd(o + 3, v.w);
}

// ---------------- launch ----------------

extern "C" void kernel_launch(void* const* d_in, const int* in_sizes, int n_in,
                              void* d_out, int out_size, void* d_ws, size_t ws_size,
                              hipStream_t stream) {
    const float* x = (const float*)d_in[0];
    const int* edge_index = (const int*)d_in[1];
    int n_edges = in_sizes[1] / 2;
    const int* src = edge_index;            // row 0: source j
    const int* dst = edge_index + n_edges;  // row 1: target i
    float* out = (float*)d_out;
    int n_nodes = out_size / D_FEAT;

    int nb = (n_nodes + BKT_NODES - 1) >> BKT_SHIFT;     // 782
    int nblk = (n_edges + CHUNK - 1) / CHUNK;            // 196

    // ws layout (u32): hist[nblk*nb] | total[nb] | offs[nb+1] | bin[E]
    size_t need = ((size_t)nblk * nb + nb + (nb + 1) + n_edges) * sizeof(u32);
    bool ok = (ws_size >= need) && (nb <= MAX_NB) && (nblk <= 256)
              && (n_nodes <= (1 << 17));
    if (!ok) {
        mp_zero_kernel<<<(out_size + 255) / 256, 256, 0, stream>>>(out, out_size);
        int total_thr = n_edges * 8;
        mp_scatter_kernel<<<(total_thr + 255) / 256, 256, 0, stream>>>(x, src, dst, out, n_edges);
        return;
    }

    u32* hist  = (u32*)d_ws;
    u32* total = hist + (size_t)nblk * nb;
    u32* offs  = total + nb;
    u32* bin   = offs + (nb + 1);

    k_zero_u32<<<(nb + 255) / 256, 256, 0, stream>>>(total, nb);
    k_hist<<<nblk, 256, 0, stream>>>(dst, hist, total, n_edges, nb);
    k_scan<<<1, 1024, 0, stream>>>(total, offs, nb, (u32)n_edges);
    k_rank<<<nb, 256, 0, stream>>>(hist, offs, nb, nblk);
    k_scatter<<<nblk, 256, 0, stream>>>(src, dst, hist, bin, n_edges, nb);
    k_gather<<<nb, 256, 0, stream>>>(x, offs, bin, out, n_nodes);
}